// Round 6
// baseline (410.444 us; speedup 1.0000x reference)
//
#include <hip/hip_runtime.h>
#include <cmath>

#define EMB 256
#define NHEAD 8
#define HD 32
#define A_LEN 512
#define TOK 32768

typedef __bf16 bf16_t;
typedef __bf16 bf16x8 __attribute__((ext_vector_type(8)));
typedef __bf16 bf16x4 __attribute__((ext_vector_type(4)));
typedef float floatx4 __attribute__((ext_vector_type(4)));

#define MFMA16(a, b, c) __builtin_amdgcn_mfma_f32_16x16x32_bf16((a), (b), (c), 0, 0, 0)

// ---------------------------------------------------------------------------
// Setup: weight_norm all 4 weights -> bf16 rows in Wall, plus RoPE cos/sin
// tables. Blocks 0..1535: one wave per weight row. Blocks 1536..1663: table.
// ---------------------------------------------------------------------------
__global__ __launch_bounds__(64) void setup_kernel(
    const float* __restrict__ proj_v, const float* __restrict__ proj_g,
    const float* __restrict__ ff_v, const float* __restrict__ ff_g,
    const float* __restrict__ w1_v, const float* __restrict__ w1_g,
    const float* __restrict__ w2_v, const float* __restrict__ w2_g,
    bf16_t* __restrict__ Wall, float* __restrict__ ctab,
    float* __restrict__ stab) {
    int b = blockIdx.x;
    int lane = threadIdx.x;
    if (b < 1536) {
        const float* v; const float* g; int r;
        if (b < 768)       { v = proj_v; g = proj_g; r = b; }
        else if (b < 1024) { v = ff_v;   g = ff_g;   r = b - 768; }
        else if (b < 1280) { v = w1_v;   g = w1_g;   r = b - 1024; }
        else               { v = w2_v;   g = w2_g;   r = b - 1280; }
        const floatx4* vr = (const floatx4*)(v + (size_t)r * 256);
        floatx4 x = vr[lane];
        float ss = x[0] * x[0] + x[1] * x[1] + x[2] * x[2] + x[3] * x[3];
#pragma unroll
        for (int off = 32; off >= 1; off >>= 1) ss += __shfl_xor(ss, off);
        float sc = g[r] * rsqrtf(ss);
        bf16x4 o;
        o[0] = (bf16_t)(x[0] * sc); o[1] = (bf16_t)(x[1] * sc);
        o[2] = (bf16_t)(x[2] * sc); o[3] = (bf16_t)(x[3] * sc);
        ((bf16x4*)(Wall + (size_t)b * 256))[lane] = o;
    } else {
        int idx = (b - 1536) * 64 + lane;     // 0..8191 = a*16 + i
        int a = idx >> 4, i = idx & 15;
        float freq = expf(-(float)(2 * i) * 0.2878231366242558f); // ln(1e4)/32
        float ang = (float)a * freq;
        ctab[idx] = cosf(ang);
        stab[idx] = sinf(ang);
    }
}

// ---------------------------------------------------------------------------
// QKV: 512 thr / 64 tokens. Wave wv owns head-group wv (96 cols): nt 0..5,
// sec = nt>>1 (q,q,k,k,v,v), d = (nt&1)*16 + lidx. LN1 -> MFMA -> RoPE ->
// q/k to [bh][a][d]; v transposed through LDS to global [bh][d][a].
// ---------------------------------------------------------------------------
__global__ __launch_bounds__(512, 4) void qkv_kernel(
    const float* __restrict__ z, const float* __restrict__ ln_g,
    const float* __restrict__ ln_b, const bf16_t* __restrict__ W,
    const float* __restrict__ pb, const float* __restrict__ ctab,
    const float* __restrict__ stab, bf16_t* __restrict__ qbf,
    bf16_t* __restrict__ kbf, bf16_t* __restrict__ vtb) {
    __shared__ bf16_t xns[64 * 264];   // 33.8 KB
    __shared__ bf16_t vls[256 * 72];   // 36.9 KB, v^T staging [vchan][a_loc]
    int tid = threadIdx.x;
    int t0 = blockIdx.x * 64;

    // ---- LN1: 2 passes x 32 rows, 16 lanes per row ----
#pragma unroll
    for (int it = 0; it < 2; ++it) {
        int row = it * 32 + (tid >> 4);
        int sub = tid & 15;
        const floatx4* zr = (const floatx4*)(z + (size_t)(t0 + row) * 256 + sub * 16);
        floatx4 v0 = zr[0], v1 = zr[1], v2 = zr[2], v3 = zr[3];
        float vals[16];
        ((floatx4*)vals)[0] = v0; ((floatx4*)vals)[1] = v1;
        ((floatx4*)vals)[2] = v2; ((floatx4*)vals)[3] = v3;
        float s = 0.f, q2 = 0.f;
#pragma unroll
        for (int i = 0; i < 16; ++i) { s += vals[i]; q2 += vals[i] * vals[i]; }
#pragma unroll
        for (int off = 8; off >= 1; off >>= 1) {
            s += __shfl_xor(s, off);
            q2 += __shfl_xor(q2, off);
        }
        float mu = s * (1.f / 256.f);
        float inv = rsqrtf(q2 * (1.f / 256.f) - mu * mu + 1e-5f);
        int cb = sub * 16;
        bf16x8 o0, o1;
#pragma unroll
        for (int i = 0; i < 8; ++i)
            o0[i] = (bf16_t)((vals[i] - mu) * inv * ln_g[cb + i] + ln_b[cb + i]);
#pragma unroll
        for (int i = 0; i < 8; ++i)
            o1[i] = (bf16_t)((vals[8 + i] - mu) * inv * ln_g[cb + 8 + i] + ln_b[cb + 8 + i]);
        *(bf16x8*)&xns[row * 264 + cb] = o0;
        *(bf16x8*)&xns[row * 264 + cb + 8] = o1;
    }
    __syncthreads();

    int wv = tid >> 6, lane = tid & 63, quad = lane >> 4, lidx = lane & 15;

    bf16x8 afr[4][8];
#pragma unroll
    for (int mt = 0; mt < 4; ++mt)
#pragma unroll
        for (int kc = 0; kc < 8; ++kc)
            afr[mt][kc] = *(const bf16x8*)&xns[(mt * 16 + lidx) * 264 + kc * 32 + quad * 8];

#pragma unroll 1
    for (int nt = 0; nt < 6; ++nt) {
        int n = wv * 96 + nt * 16 + lidx;
        bf16x8 bfr[8];
#pragma unroll
        for (int kc = 0; kc < 8; ++kc)
            bfr[kc] = *(const bf16x8*)&W[(size_t)n * 256 + kc * 32 + quad * 8];
        floatx4 acc[4];
#pragma unroll
        for (int mt = 0; mt < 4; ++mt) acc[mt] = (floatx4){0.f, 0.f, 0.f, 0.f};
#pragma unroll
        for (int kc = 0; kc < 8; ++kc)
#pragma unroll
            for (int mt = 0; mt < 4; ++mt)
                acc[mt] = MFMA16(afr[mt][kc], bfr[kc], acc[mt]);

        float bias = pb[n];
        int sec = nt >> 1;                 // 0=q 1=k 2=v
        int d = (nt & 1) * 16 + lidx;      // dim within head; head = wv
#pragma unroll
        for (int mt = 0; mt < 4; ++mt) {
#pragma unroll
            for (int r = 0; r < 4; ++r) {
                int tok = t0 + mt * 16 + quad * 4 + r;
                int a = tok & 511;
                int bu = tok >> 9;
                float val = acc[mt][r] + bias;
                if (sec == 2) {
                    int a_loc = mt * 16 + quad * 4 + r;
                    vls[(wv * 32 + d) * 72 + a_loc] = (bf16_t)val;
                } else {
                    size_t addr = ((size_t)((bu * 8 + wv) * 512 + a)) * 32 + d;
                    float part = __shfl_xor(val, 1);
                    float cs = ctab[a * 16 + (d >> 1)];
                    float sn = stab[a * 16 + (d >> 1)];
                    float res = ((d & 1) == 0) ? (val * cs - part * sn)
                                               : (val * cs + part * sn);
                    if (sec == 0)
                        qbf[addr] = (bf16_t)(res * 0.17677669529663687f);
                    else
                        kbf[addr] = (bf16_t)res;
                }
            }
        }
    }
    __syncthreads();
    // flush v^T: 256 rows x 128 B; wave covers 8 rows fully -> coalesced
    {
        int bu = t0 >> 9, a0 = t0 & 511;
#pragma unroll
        for (int ps = 0; ps < 4; ++ps) {
            int c = ps * 512 + tid;         // 16B chunk id, 0..2047
            int row = c >> 3, col8 = c & 7;
            *(bf16x8*)&vtb[((size_t)(bu * 256 + row)) * 512 + a0 + col8 * 8] =
                *(const bf16x8*)&vls[row * 72 + col8 * 8];
        }
    }
}

// ---------------------------------------------------------------------------
// Attention: one block (512 thr = 8 waves) per (bu,h). No online max
// (exp(s-8) via MFMA C-init; softmax shift-invariant -> exact). Row sums via
// ones-B-frag MFMA (no shuffles). LDS exactly 80 KB -> 2 blocks/CU.
// ---------------------------------------------------------------------------
__global__ __launch_bounds__(512, 4) void attn_kernel(
    const bf16_t* __restrict__ qbf, const bf16_t* __restrict__ kbf,
    const bf16_t* __restrict__ vtb, bf16_t* __restrict__ ob) {
    __shared__ bf16_t Kls[512 * 32];      // 32 KB
    __shared__ bf16_t Vt[32 * 512];       // 32 KB
    __shared__ bf16_t Pls[8 * 16 * 64];   // 16 KB
    int tid = threadIdx.x;
    int wv = tid >> 6, lane = tid & 63, quad = lane >> 4, lidx = lane & 15;
    int bh = blockIdx.x;
    int bu = bh >> 3, h = bh & 7;
    size_t hb = (size_t)bh * (A_LEN * HD);

    // ---- stage K (row-swizzled) and V^T (pre-transposed in global) ----
#pragma unroll
    for (int i = 0; i < 4; ++i) {
        int c = tid + i * 512;            // 16B chunk id, 0..2047
        int key = c >> 2, blk = c & 3;
        bf16x8 kv = *(const bf16x8*)&kbf[hb + (size_t)c * 8];
        *(bf16x8*)&Kls[key * 32 + ((blk ^ (key & 3)) << 3)] = kv;
        int vrow = c >> 6, vblk = c & 63;
        bf16x8 vv = *(const bf16x8*)&vtb[hb + (size_t)c * 8];
        *(bf16x8*)&Vt[vrow * 512 + ((vblk ^ (vrow & 7)) << 3)] = vv;
    }
    __syncthreads();

    int pbase = wv * (16 * 64);
    const floatx4 cm8 = (floatx4){-8.f, -8.f, -8.f, -8.f};
    const floatx4 zero4 = (floatx4){0.f, 0.f, 0.f, 0.f};
    bf16x8 ones;
#pragma unroll
    for (int j = 0; j < 8; ++j) ones[j] = (bf16_t)1.0f;

#pragma unroll 1
    for (int mt = 0; mt < 4; ++mt) {
        int q0 = wv * 64 + mt * 16;
        bf16x8 qfrag = *(const bf16x8*)&qbf[hb + (size_t)(q0 + lidx) * 32 + quad * 8];
        floatx4 Oacc[2], lacc;
        Oacc[0] = zero4; Oacc[1] = zero4; lacc = zero4;

#pragma unroll 2
        for (int kc = 0; kc < 8; ++kc) {
            floatx4 sc[4];
#pragma unroll
            for (int t = 0; t < 4; ++t) {
                bf16x8 kf = *(const bf16x8*)&Kls[(kc * 64 + t * 16 + lidx) * 32 +
                                                 ((quad ^ (lidx & 3)) << 3)];
                sc[t] = MFMA16(qfrag, kf, cm8);   // s - 8 folded into C
            }
            // exp + store P (C-layout -> swizzled [row][col])
#pragma unroll
            for (int t = 0; t < 4; ++t)
#pragma unroll
                for (int r = 0; r < 4; ++r) {
                    float p = __expf(sc[t][r]);
                    int row = quad * 4 + r;
                    int pc = (t * 16 + lidx) ^ ((row & 7) << 3);
                    Pls[pbase + row * 64 + pc] = (bf16_t)p;
                }
            // PV + row-sum via ones-MFMA (reuses pf)
#pragma unroll
            for (int ks = 0; ks < 2; ++ks) {
                bf16x8 pf = *(const bf16x8*)&Pls[pbase + lidx * 64 +
                                                 (((ks * 4 + quad) ^ (lidx & 7)) << 3)];
                lacc = MFMA16(pf, ones, lacc);
#pragma unroll
                for (int nt = 0; nt < 2; ++nt) {
                    int vrow = nt * 16 + lidx;
                    bf16x8 vf = *(const bf16x8*)&Vt[vrow * 512 +
                        ((kc * 8 + ((ks * 4 + quad) ^ (lidx & 7))) << 3)];
                    Oacc[nt] = MFMA16(pf, vf, Oacc[nt]);
                }
            }
        }
#pragma unroll
        for (int r = 0; r < 4; ++r) {
            float inv = 1.f / lacc[r];
            int tok = bu * 512 + q0 + quad * 4 + r;
#pragma unroll
            for (int nt = 0; nt < 2; ++nt)
                ob[(size_t)tok * 256 + h * 32 + nt * 16 + lidx] =
                    (bf16_t)(Oacc[nt][r] * inv);
        }
    }
}

// ---------------------------------------------------------------------------
// Fused tail: out = r1 + FFN(LN2(r1)), r1 = z + attn@Wo^T + ff_b.
// 512 thr / 64 tokens; wave owns 32 N-cols. Output staged through LDS
// (overlaying dead xns/hs) for full-line coalesced fp32 writes.
// ---------------------------------------------------------------------------
__global__ __launch_bounds__(512, 4) void tail_kernel(
    const bf16_t* __restrict__ X, const bf16_t* __restrict__ Wo,
    const float* __restrict__ obias, const float* __restrict__ zin,
    const float* __restrict__ ln_g, const float* __restrict__ ln_b,
    const bf16_t* __restrict__ W1, const float* __restrict__ b1,
    const bf16_t* __restrict__ W2, const float* __restrict__ b2,
    float* __restrict__ outp) {
    __shared__ __align__(16) char smem[67584];   // xns|hs union; fp32 stage
    __shared__ float red[64 * 16];
    __shared__ float mi[64 * 2];
    bf16_t* xns = (bf16_t*)smem;                 // [64][264]
    bf16_t* hs  = (bf16_t*)(smem + 33792);       // [64][264]
    float* stage = (float*)smem;                 // [64][260] overlay at end
    int tid = threadIdx.x;
    int t0 = blockIdx.x * 64;
    int wv = tid >> 6, lane = tid & 63, quad = lane >> 4, lidx = lane & 15;

    // ---- o-proj GEMM: r1 = z + X@Wo^T + ff_b (regs) ----
    bf16x8 afr[4][8];
#pragma unroll
    for (int mt = 0; mt < 4; ++mt)
#pragma unroll
        for (int kc = 0; kc < 8; ++kc)
            afr[mt][kc] = *(const bf16x8*)&X[(size_t)(t0 + mt * 16 + lidx) * 256 + kc * 32 + quad * 8];

    float r1[2][4][4];   // [nt][mt][r]
#pragma unroll 1
    for (int nt = 0; nt < 2; ++nt) {
        int n = wv * 32 + nt * 16 + lidx;
        bf16x8 bfr[8];
#pragma unroll
        for (int kc = 0; kc < 8; ++kc)
            bfr[kc] = *(const bf16x8*)&Wo[(size_t)n * 256 + kc * 32 + quad * 8];
        floatx4 acc[4];
#pragma unroll
        for (int mt = 0; mt < 4; ++mt) acc[mt] = (floatx4){0.f, 0.f, 0.f, 0.f};
#pragma unroll
        for (int kc = 0; kc < 8; ++kc)
#pragma unroll
            for (int mt = 0; mt < 4; ++mt)
                acc[mt] = MFMA16(afr[mt][kc], bfr[kc], acc[mt]);
        float b = obias[n];
#pragma unroll
        for (int mt = 0; mt < 4; ++mt)
#pragma unroll
            for (int r = 0; r < 4; ++r) {
                size_t o = (size_t)(t0 + mt * 16 + quad * 4 + r) * 256 + n;
                r1[nt][mt][r] = zin[o] + acc[mt][r] + b;
            }
    }

    // ---- LN2 stats: lane partial over 2 nt -> shuffle over lidx -> LDS ----
#pragma unroll
    for (int mt = 0; mt < 4; ++mt)
#pragma unroll
        for (int r = 0; r < 4; ++r) {
            float s = r1[0][mt][r] + r1[1][mt][r];
            float ss = r1[0][mt][r] * r1[0][mt][r] + r1[1][mt][r] * r1[1][mt][r];
#pragma unroll
            for (int off = 8; off >= 1; off >>= 1) {
                s += __shfl_xor(s, off);
                ss += __shfl_xor(ss, off);
            }
            if (lidx == 0) {
                int row = mt * 16 + quad * 4 + r;
                red[row * 16 + wv * 2] = s;
                red[row * 16 + wv * 2 + 1] = ss;
            }
        }
    __syncthreads();
    if (tid < 64) {
        float s = 0.f, ss = 0.f;
#pragma unroll
        for (int w = 0; w < 8; ++w) {
            s += red[tid * 16 + w * 2];
            ss += red[tid * 16 + w * 2 + 1];
        }
        float mu = s * (1.f / 256.f);
        mi[tid * 2] = mu;
        mi[tid * 2 + 1] = rsqrtf(ss * (1.f / 256.f) - mu * mu + 1e-5f);
    }
    __syncthreads();

    // ---- write xn = LN2(r1) to LDS (bf16) ----
    float gv[2], bv[2];
#pragma unroll
    for (int nt = 0; nt < 2; ++nt) {
        int n = wv * 32 + nt * 16 + lidx;
        gv[nt] = ln_g[n]; bv[nt] = ln_b[n];
    }
#pragma unroll
    for (int mt = 0; mt < 4; ++mt)
#pragma unroll
        for (int r = 0; r < 4; ++r) {
            int row = mt * 16 + quad * 4 + r;
            float mu = mi[row * 2], inv = mi[row * 2 + 1];
#pragma unroll
            for (int nt = 0; nt < 2; ++nt) {
                int n = wv * 32 + nt * 16 + lidx;
                xns[row * 264 + n] = (bf16_t)((r1[nt][mt][r] - mu) * inv * gv[nt] + bv[nt]);
            }
        }
    __syncthreads();

    // ---- FFN1: h = gelu(xn@W1^T + b1) -> hs ----
#pragma unroll
    for (int mt = 0; mt < 4; ++mt)
#pragma unroll
        for (int kc = 0; kc < 8; ++kc)
            afr[mt][kc] = *(const bf16x8*)&xns[(mt * 16 + lidx) * 264 + kc * 32 + quad * 8];
#pragma unroll 1
    for (int nt = 0; nt < 2; ++nt) {
        int n = wv * 32 + nt * 16 + lidx;
        bf16x8 bfr[8];
#pragma unroll
        for (int kc = 0; kc < 8; ++kc)
            bfr[kc] = *(const bf16x8*)&W1[(size_t)n * 256 + kc * 32 + quad * 8];
        floatx4 acc[4];
#pragma unroll
        for (int mt = 0; mt < 4; ++mt) acc[mt] = (floatx4){0.f, 0.f, 0.f, 0.f};
#pragma unroll
        for (int kc = 0; kc < 8; ++kc)
#pragma unroll
            for (int mt = 0; mt < 4; ++mt)
                acc[mt] = MFMA16(afr[mt][kc], bfr[kc], acc[mt]);
        float b = b1[n];
#pragma unroll
        for (int mt = 0; mt < 4; ++mt)
#pragma unroll
            for (int r = 0; r < 4; ++r) {
                float x = acc[mt][r] + b;
                float gel = 0.5f * x * (1.f + erff(x * 0.7071067811865476f));
                hs[(mt * 16 + quad * 4 + r) * 264 + n] = (bf16_t)gel;
            }
    }
    __syncthreads();

    // ---- FFN2: r1 += h@W2^T + b2 ----
#pragma unroll
    for (int mt = 0; mt < 4; ++mt)
#pragma unroll
        for (int kc = 0; kc < 8; ++kc)
            afr[mt][kc] = *(const bf16x8*)&hs[(mt * 16 + lidx) * 264 + kc * 32 + quad * 8];
#pragma unroll 1
    for (int nt = 0; nt < 2; ++nt) {
        int n = wv * 32 + nt * 16 + lidx;
        bf16x8 bfr[8];
#pragma unroll
        for (int kc = 0; kc < 8; ++kc)
            bfr[kc] = *(const bf16x8*)&W2[(size_t)n * 256 + kc * 32 + quad * 8];
        floatx4 acc[4];
#pragma unroll
        for (int mt = 0; mt < 4; ++mt) acc[mt] = (floatx4){0.f, 0.f, 0.f, 0.f};
#pragma unroll
        for (int kc = 0; kc < 8; ++kc)
#pragma unroll
            for (int mt = 0; mt < 4; ++mt)
                acc[mt] = MFMA16(afr[mt][kc], bfr[kc], acc[mt]);
        float b = b2[n];
#pragma unroll
        for (int mt = 0; mt < 4; ++mt)
#pragma unroll
            for (int r = 0; r < 4; ++r)
                r1[nt][mt][r] += acc[mt][r] + b;
    }
    __syncthreads();   // all reads of xns/hs complete -> safe to overlay

    // ---- stage fp32 out, then full-line coalesced writes ----
#pragma unroll
    for (int mt = 0; mt < 4; ++mt)
#pragma unroll
        for (int r = 0; r < 4; ++r) {
            int row = mt * 16 + quad * 4 + r;
#pragma unroll
            for (int nt = 0; nt < 2; ++nt)
                stage[row * 260 + wv * 32 + nt * 16 + lidx] = r1[nt][mt][r];
        }
    __syncthreads();
#pragma unroll
    for (int ps = 0; ps < 8; ++ps) {
        int c = ps * 512 + tid;            // float4 chunk id, 0..4095
        int row = c >> 6, c4 = c & 63;     // wave = one full 1KB row
        floatx4 v = *(const floatx4*)&stage[row * 260 + c4 * 4];
        *(floatx4*)&outp[(size_t)(t0 + row) * 256 + c4 * 4] = v;
    }
}

// ---------------------------------------------------------------------------
extern "C" void kernel_launch(void* const* d_in, const int* in_sizes, int n_in,
                              void* d_out, int out_size, void* d_ws, size_t ws_size,
                              hipStream_t stream) {
    const float* z      = (const float*)d_in[0];
    const float* ln1_g  = (const float*)d_in[1];
    const float* ln1_b  = (const float*)d_in[2];
    const float* proj_v = (const float*)d_in[3];
    const float* proj_g = (const float*)d_in[4];
    const float* proj_b = (const float*)d_in[5];
    const float* ff_v   = (const float*)d_in[6];
    const float* ff_g   = (const float*)d_in[7];
    const float* ff_b   = (const float*)d_in[8];
    const float* ln2_g  = (const float*)d_in[9];
    const float* ln2_b  = (const float*)d_in[10];
    const float* w1_v   = (const float*)d_in[11];
    const float* w1_g   = (const float*)d_in[12];
    const float* w1_b   = (const float*)d_in[13];
    const float* w2_v   = (const float*)d_in[14];
    const float* w2_g   = (const float*)d_in[15];
    const float* w2_b   = (const float*)d_in[16];
    float* out = (float*)d_out;

    char* p = (char*)d_ws;
    bf16_t* Wall = (bf16_t*)p; p += (size_t)1536 * 256 * 2;
    float* ctab  = (float*)p;  p += 8192 * 4;
    float* stab  = (float*)p;  p += 8192 * 4;
    // q/k: [bh][a][d]; vtb: [bh][d][a]; each 512*512*32 = TOK*256 elems
    bf16_t* qbf  = (bf16_t*)p; p += (size_t)TOK * 256 * 2;
    bf16_t* kbf  = (bf16_t*)p; p += (size_t)TOK * 256 * 2;
    bf16_t* vtb  = (bf16_t*)p; p += (size_t)TOK * 256 * 2;
    bf16_t* abuf = (bf16_t*)p; p += (size_t)TOK * 256 * 2;

    const bf16_t* Wqkv = Wall;
    const bf16_t* Wo   = Wall + (size_t)768 * 256;
    const bf16_t* W1   = Wall + (size_t)1024 * 256;
    const bf16_t* W2   = Wall + (size_t)1280 * 256;

    setup_kernel<<<1664, 64, 0, stream>>>(proj_v, proj_g, ff_v, ff_g,
                                          w1_v, w1_g, w2_v, w2_g,
                                          Wall, ctab, stab);
    qkv_kernel<<<TOK / 64, 512, 0, stream>>>(z, ln1_g, ln1_b, Wqkv, proj_b,
                                             ctab, stab, qbf, kbf, vtb);
    attn_kernel<<<64 * 8, 512, 0, stream>>>(qbf, kbf, vtb, abuf);
    tail_kernel<<<TOK / 64, 512, 0, stream>>>(abuf, Wo, ff_b, z, ln2_g, ln2_b,
                                              W1, w1_b, W2, w2_b, out);
}